// Round 8
// baseline (243.866 us; speedup 1.0000x reference)
//
#include <hip/hip_runtime.h>
#include <hip/hip_fp16.h>

#define N_NODES 100000
#define N_EDGES 1600000
#define D 64
#define BN_EPS 1e-5f
#define NBKT 256
#define NPB 391                  // nodes per bucket: 256*391 = 100096 >= 100000
#define BKT_CAP 8192             // expected ~6250/bucket, sigma ~79
#define SORT_T 1024

typedef _Float16 half8 __attribute__((ext_vector_type(8)));
typedef float f32x4 __attribute__((ext_vector_type(4)));

// ---------------------------------------------------------------------------
// Bucket pass: split edges into 256 dst-range buckets ((src,dst) int2).
// ---------------------------------------------------------------------------
__global__ __launch_bounds__(256) void bucket_k(
    const int* __restrict__ src, const int* __restrict__ dst,
    int* __restrict__ bkt_cnt, int2* __restrict__ bktbuf)
{
    __shared__ int h[NBKT], base[NBKT], cur[NBKT];
    const int t = threadIdx.x;
    if (t < NBKT) { h[t] = 0; cur[t] = 0; }
    __syncthreads();
    const int e0 = blockIdx.x * 4096;
    int s[16], d[16], b[16];
    #pragma unroll
    for (int i = 0; i < 16; ++i) {
        int e = e0 + i * 256 + t;
        if (e < N_EDGES) {
            s[i] = src[e];
            d[i] = dst[e];
            b[i] = d[i] / NPB;
            atomicAdd(&h[b[i]], 1);
        } else {
            b[i] = -1;
        }
    }
    __syncthreads();
    if (t < NBKT) base[t] = atomicAdd(&bkt_cnt[t], h[t]);
    __syncthreads();
    #pragma unroll
    for (int i = 0; i < 16; ++i) {
        if (b[i] >= 0) {
            int p = atomicAdd(&cur[b[i]], 1);
            bktbuf[(size_t)b[i] * BKT_CAP + base[b[i]] + p] = make_int2(s[i], d[i]);
        }
    }
}

// ---------------------------------------------------------------------------
// sort_k: one block per bucket. LDS counting sort -> rowptr segment + col.
// ---------------------------------------------------------------------------
__global__ __launch_bounds__(SORT_T) void sort_k(
    const int2* __restrict__ bktbuf, const int* __restrict__ bkt_cnt,
    int* __restrict__ rowptr, int* __restrict__ col)
{
    __shared__ int h[NPB];
    __shared__ int cur[NPB];
    __shared__ int part[SORT_T];
    __shared__ int bsc[NBKT];

    const int b = blockIdx.x;
    const int t = threadIdx.x;
    const int nb0 = b * NPB;
    const int nodes_in = min(NPB, N_NODES - nb0);
    const int cnt = bkt_cnt[b];
    const int2* buf = bktbuf + (size_t)b * BKT_CAP;

    if (t < NBKT) bsc[t] = bkt_cnt[t];
    __syncthreads();
    for (int off = 1; off < NBKT; off <<= 1) {
        int x = 0;
        if (t < NBKT) {
            x = bsc[t];
            if (t >= off) x += bsc[t - off];
        }
        __syncthreads();
        if (t < NBKT) bsc[t] = x;
        __syncthreads();
    }
    const int gbase = bsc[b] - cnt;

    if (t < NPB) h[t] = 0;
    __syncthreads();

    for (int i = t; i < cnt; i += SORT_T)
        atomicAdd(&h[buf[i].y - nb0], 1);
    __syncthreads();

    int a = (t < NPB) ? h[t] : 0;
    part[t] = a;
    __syncthreads();
    for (int off = 1; off < SORT_T; off <<= 1) {
        int x = part[t];
        int u = (t >= off) ? part[t - off] : 0;
        __syncthreads();
        part[t] = x + u;
        __syncthreads();
    }
    int excl = part[t] - a;
    if (t < NPB) {
        cur[t] = excl;
        if (t < nodes_in) rowptr[nb0 + t] = gbase + excl;
    }
    if (b == NBKT - 1 && t == 0) rowptr[N_NODES] = N_EDGES;
    __syncthreads();

    for (int i = t; i < cnt; i += SORT_T) {
        int2 r = buf[i];
        int slot = atomicAdd(&cur[r.y - nb0], 1);
        col[gbase + slot] = r.x;
    }
}

// ---------------------------------------------------------------------------
// conv_k: feat fp32 -> fp16 table.
// ---------------------------------------------------------------------------
__global__ __launch_bounds__(256) void conv_k(
    const float* __restrict__ feat, __half* __restrict__ feat16)
{
    size_t i = ((size_t)blockIdx.x * 256 + threadIdx.x) * 8;
    if (i < (size_t)N_NODES * D) {
        float4 v0 = *(const float4*)(feat + i);
        float4 v1 = *(const float4*)(feat + i + 4);
        __half2 o[4];
        o[0] = __floats2half2_rn(v0.x, v0.y);
        o[1] = __floats2half2_rn(v0.z, v0.w);
        o[2] = __floats2half2_rn(v1.x, v1.y);
        o[3] = __floats2half2_rn(v1.z, v1.w);
        *(float4*)(feat16 + i) = *(float4*)o;
    }
}

// ---------------------------------------------------------------------------
// gather16_k: one wave per node, fp16 rows (128B/edge), fp32 accumulate.
// Writes x = (1+eps)*feat + neigh in fp16.
// ---------------------------------------------------------------------------
__global__ __launch_bounds__(256) void gather16_k(
    const __half* __restrict__ feat16, const int* __restrict__ rowptr,
    const int* __restrict__ col, const float* __restrict__ epsp,
    __half* __restrict__ x16)
{
    int node = blockIdx.x * 4 + (threadIdx.x >> 6);
    int lane = threadIdx.x & 63;
    if (node >= N_NODES) return;
    int g = lane >> 3;
    int c = (lane & 7) << 3;
    int lo = rowptr[node];
    int hi = rowptr[node + 1];
    float a[8] = {0.f, 0.f, 0.f, 0.f, 0.f, 0.f, 0.f, 0.f};
    int e = lo + g;
    for (; e + 8 < hi; e += 16) {
        int s0 = col[e];
        int s1 = col[e + 8];
        float4 r0 = *(const float4*)(feat16 + (size_t)s0 * D + c);
        float4 r1 = *(const float4*)(feat16 + (size_t)s1 * D + c);
        const __half2* h0 = (const __half2*)&r0;
        const __half2* h1 = (const __half2*)&r1;
        #pragma unroll
        for (int i = 0; i < 4; ++i) {
            float2 f0 = __half22float2(h0[i]);
            float2 f1 = __half22float2(h1[i]);
            a[2 * i]     += f0.x + f1.x;
            a[2 * i + 1] += f0.y + f1.y;
        }
    }
    if (e < hi) {
        float4 r0 = *(const float4*)(feat16 + (size_t)col[e] * D + c);
        const __half2* h0 = (const __half2*)&r0;
        #pragma unroll
        for (int i = 0; i < 4; ++i) {
            float2 f0 = __half22float2(h0[i]);
            a[2 * i]     += f0.x;
            a[2 * i + 1] += f0.y;
        }
    }
    #pragma unroll
    for (int off = 8; off <= 32; off <<= 1)
        #pragma unroll
        for (int i = 0; i < 8; ++i)
            a[i] += __shfl_xor(a[i], off, 64);
    if (g == 0) {
        float4 rs = *(const float4*)(feat16 + (size_t)node * D + c);
        const __half2* hs = (const __half2*)&rs;
        const float epsv = 1.0f + epsp[0];
        __half2 o[4];
        #pragma unroll
        for (int i = 0; i < 4; ++i) {
            float2 fs = __half22float2(hs[i]);
            o[i] = __floats2half2_rn(fmaf(epsv, fs.x, a[2 * i]),
                                     fmaf(epsv, fs.y, a[2 * i + 1]));
        }
        *(float4*)(x16 + (size_t)node * D + c) = *(float4*)o;
    }
}

// ---------------------------------------------------------------------------
// gather32_k (fp32 fallback).
// ---------------------------------------------------------------------------
__global__ __launch_bounds__(256) void gather32_k(
    const float* __restrict__ feat, const int* __restrict__ rowptr,
    const int* __restrict__ col, const float* __restrict__ epsp,
    float* __restrict__ x)
{
    int node = blockIdx.x * 4 + (threadIdx.x >> 6);
    int lane = threadIdx.x & 63;
    if (node >= N_NODES) return;
    int g = lane >> 4;
    int c = (lane & 15) << 2;
    int lo = rowptr[node];
    int hi = rowptr[node + 1];
    float ax = 0.f, ay = 0.f, az = 0.f, aw = 0.f;
    int e = lo + g;
    for (; e + 4 < hi; e += 8) {
        int s0 = col[e];
        int s1 = col[e + 4];
        float4 v0 = *(const float4*)(feat + (size_t)s0 * D + c);
        float4 v1 = *(const float4*)(feat + (size_t)s1 * D + c);
        ax += v0.x; ay += v0.y; az += v0.z; aw += v0.w;
        ax += v1.x; ay += v1.y; az += v1.z; aw += v1.w;
    }
    if (e < hi) {
        float4 v = *(const float4*)(feat + (size_t)col[e] * D + c);
        ax += v.x; ay += v.y; az += v.z; aw += v.w;
    }
    #pragma unroll
    for (int off = 16; off <= 32; off <<= 1) {
        ax += __shfl_xor(ax, off, 64);
        ay += __shfl_xor(ay, off, 64);
        az += __shfl_xor(az, off, 64);
        aw += __shfl_xor(aw, off, 64);
    }
    if (g == 0) {
        float4 f = *(const float4*)(feat + (size_t)node * D + c);
        const float epsv = 1.0f + epsp[0];
        float4 r;
        r.x = fmaf(epsv, f.x, ax);
        r.y = fmaf(epsv, f.y, ay);
        r.z = fmaf(epsv, f.z, az);
        r.w = fmaf(epsv, f.w, aw);
        *(float4*)(x + (size_t)node * D + c) = r;
    }
}

// ---------------------------------------------------------------------------
// mfma_mlp_k: 64-node tile, fp16 MFMA (16x16x32), fp32 accumulate.
// Wave w owns nodes w*16..w*16+15. LDS: W1T/W2T [n][k] fp16 stride 72
// (b128 frag reads 2-way/bank = free), xts [node][k] stride 72 (x, then
// relu-t, then h2 staging). h2 stored fp16. BN partials from C-layout
// (col = lane&15) via shfl_xor(16,32).
// ---------------------------------------------------------------------------
__global__ __launch_bounds__(256) void mfma_mlp_k(
    const __half* __restrict__ x16,
    const float* __restrict__ W1, const float* __restrict__ b1,
    const float* __restrict__ W2, const float* __restrict__ b2,
    __half* __restrict__ h216, float* __restrict__ stats8)
{
    __shared__ __align__(16) _Float16 W1T[64 * 72];
    __shared__ __align__(16) _Float16 W2T[64 * 72];
    __shared__ __align__(16) _Float16 xts[64 * 72];
    __shared__ float b1s[64], b2s[64];

    const int t  = threadIdx.x;
    const int nb = blockIdx.x * 64;

    // stage W1^T / W2^T as fp16 (thread reads quarter-row k of W)
    {
        const int k  = t >> 2;
        const int n0 = (t & 3) * 16;
        #pragma unroll
        for (int j = 0; j < 16; j += 4) {
            float4 w1 = *(const float4*)(W1 + k * 64 + n0 + j);
            float4 w2 = *(const float4*)(W2 + k * 64 + n0 + j);
            W1T[(n0 + j + 0) * 72 + k] = (_Float16)w1.x;
            W1T[(n0 + j + 1) * 72 + k] = (_Float16)w1.y;
            W1T[(n0 + j + 2) * 72 + k] = (_Float16)w1.z;
            W1T[(n0 + j + 3) * 72 + k] = (_Float16)w1.w;
            W2T[(n0 + j + 0) * 72 + k] = (_Float16)w2.x;
            W2T[(n0 + j + 1) * 72 + k] = (_Float16)w2.y;
            W2T[(n0 + j + 2) * 72 + k] = (_Float16)w2.z;
            W2T[(n0 + j + 3) * 72 + k] = (_Float16)w2.w;
        }
    }
    if (t < 64)       b1s[t]      = b1[t];
    else if (t < 128) b2s[t - 64] = b2[t - 64];

    // stage x rows (fp16 memcpy, 32B per thread)
    {
        const int n = t >> 2;
        const int c = (t & 3) * 16;
        const int gn = nb + n;
        float4 r0 = make_float4(0.f, 0.f, 0.f, 0.f), r1 = r0;
        if (gn < N_NODES) {
            r0 = *(const float4*)(x16 + (size_t)gn * 64 + c);
            r1 = *(const float4*)(x16 + (size_t)gn * 64 + c + 8);
        }
        *(float4*)&xts[n * 72 + c]     = r0;
        *(float4*)&xts[n * 72 + c + 8] = r1;
    }
    __syncthreads();

    const int w     = t >> 6;
    const int lane  = t & 63;
    const int m     = lane & 15;    // A row within wave tile / C col
    const int h     = lane >> 4;    // k-subchunk
    const int rbase = w * 16;

    const _Float16* xw = &xts[(rbase + m) * 72 + h * 8];
    half8 a0 = *(const half8*)(xw);
    half8 a1 = *(const half8*)(xw + 32);

    f32x4 acc[4];
    #pragma unroll
    for (int jt = 0; jt < 4; ++jt) {
        const float bias = b1s[jt * 16 + m];
        acc[jt] = (f32x4){bias, bias, bias, bias};
        const _Float16* bw = &W1T[(jt * 16 + m) * 72 + h * 8];
        half8 bf0 = *(const half8*)(bw);
        half8 bf1 = *(const half8*)(bw + 32);
        acc[jt] = __builtin_amdgcn_mfma_f32_16x16x32_f16(a0, bf0, acc[jt], 0, 0, 0);
        acc[jt] = __builtin_amdgcn_mfma_f32_16x16x32_f16(a1, bf1, acc[jt], 0, 0, 0);
    }

    // relu -> t (overwrite own wave's xts rows; a0/a1 already in regs)
    #pragma unroll
    for (int jt = 0; jt < 4; ++jt)
        #pragma unroll
        for (int r = 0; r < 4; ++r)
            xts[(rbase + h * 4 + r) * 72 + jt * 16 + m] =
                (_Float16)fmaxf(acc[jt][r], 0.0f);
    __syncthreads();

    half8 c0 = *(const half8*)(xw);
    half8 c1 = *(const half8*)(xw + 32);

    f32x4 acc2[4];
    #pragma unroll
    for (int jt = 0; jt < 4; ++jt) {
        const float bias = b2s[jt * 16 + m];
        acc2[jt] = (f32x4){bias, bias, bias, bias};
        const _Float16* bw = &W2T[(jt * 16 + m) * 72 + h * 8];
        half8 bf0 = *(const half8*)(bw);
        half8 bf1 = *(const half8*)(bw + 32);
        acc2[jt] = __builtin_amdgcn_mfma_f32_16x16x32_f16(c0, bf0, acc2[jt], 0, 0, 0);
        acc2[jt] = __builtin_amdgcn_mfma_f32_16x16x32_f16(c1, bf1, acc2[jt], 0, 0, 0);
    }

    // BN partials (exclude padded rows) + stage h2 into xts
    float psums[4], psqs[4];
    #pragma unroll
    for (int jt = 0; jt < 4; ++jt) {
        float ps = 0.f, pq = 0.f;
        #pragma unroll
        for (int r = 0; r < 4; ++r) {
            const int row = rbase + h * 4 + r;
            const float v = acc2[jt][r];
            const float vv = (nb + row < N_NODES) ? v : 0.f;
            ps += vv;
            pq += vv * vv;
            xts[row * 72 + jt * 16 + m] = (_Float16)v;
        }
        ps += __shfl_xor(ps, 16, 64); ps += __shfl_xor(ps, 32, 64);
        pq += __shfl_xor(pq, 16, 64); pq += __shfl_xor(pq, 32, 64);
        psums[jt] = ps; psqs[jt] = pq;
    }
    if (lane < 16) {
        float* sp = stats8 + (size_t)(blockIdx.x & 7) * 128;
        #pragma unroll
        for (int jt = 0; jt < 4; ++jt) {
            unsafeAtomicAdd(sp + jt * 16 + lane,      psums[jt]);
            unsafeAtomicAdd(sp + 64 + jt * 16 + lane, psqs[jt]);
        }
    }
    __syncthreads();

    // coalesced fp16 h2 store: wave stores its own 16 rows (32B/lane)
    {
        const int rr = lane >> 2;
        const int cc = (lane & 3) * 16;
        const int gn = nb + rbase + rr;
        if (gn < N_NODES) {
            float4 r0 = *(const float4*)&xts[(rbase + rr) * 72 + cc];
            float4 r1 = *(const float4*)&xts[(rbase + rr) * 72 + cc + 8];
            *(float4*)(h216 + (size_t)gn * 64 + cc)     = r0;
            *(float4*)(h216 + (size_t)gn * 64 + cc + 8) = r1;
        }
    }
}

// ---------------------------------------------------------------------------
// mlp32_k (fp32 fallback): scalar-FMA MLP, h2 fp32 into h2out.
// ---------------------------------------------------------------------------
__global__ __launch_bounds__(256) void mlp32_k(
    const float* __restrict__ x,
    const float* __restrict__ W1, const float* __restrict__ b1,
    const float* __restrict__ W2, const float* __restrict__ b2,
    float* __restrict__ h2out, float* __restrict__ stats8)
{
    __shared__ float W1s[64 * 68];
    __shared__ float W2s[64 * 68];
    __shared__ float xs[64 * 65];
    __shared__ float b1s[64], b2s[64];

    const int t  = threadIdx.x;
    const int nb = blockIdx.x * 64;

    #pragma unroll
    for (int i = 0; i < 4; ++i) {
        int l  = t + i * 256;
        int k  = l >> 4;
        int j4 = (l & 15) << 2;
        *(float4*)(&W1s[k * 68 + j4]) = *(const float4*)(W1 + k * 64 + j4);
        *(float4*)(&W2s[k * 68 + j4]) = *(const float4*)(W2 + k * 64 + j4);
    }
    if (t < 64)       b1s[t]      = b1[t];
    else if (t < 128) b2s[t - 64] = b2[t - 64];

    #pragma unroll
    for (int i = 0; i < 2; ++i) {
        int n  = (t >> 3) + i * 32;
        int k8 = (t & 7) << 3;
        int gn = nb + n;
        float4 a = make_float4(0.f, 0.f, 0.f, 0.f), b = a;
        if (gn < N_NODES) {
            a = *(const float4*)(x + (size_t)gn * D + k8);
            b = *(const float4*)(x + (size_t)gn * D + k8 + 4);
        }
        *(float4*)&xs[n * 65 + k8]     = a;
        *(float4*)&xs[n * 65 + k8 + 4] = b;
    }
    __syncthreads();

    const int n0 = (t & 15) << 2;
    const int j0 = (t >> 4) << 2;
    const float* xr0 = &xs[(n0 + 0) * 65];
    const float* xr1 = &xs[(n0 + 1) * 65];
    const float* xr2 = &xs[(n0 + 2) * 65];
    const float* xr3 = &xs[(n0 + 3) * 65];

    float acc[4][4];
    #pragma unroll
    for (int a = 0; a < 4; ++a)
        #pragma unroll
        for (int b = 0; b < 4; ++b)
            acc[a][b] = b1s[j0 + b];

    #pragma unroll 8
    for (int k = 0; k < 64; ++k) {
        const float4 w = *(const float4*)(&W1s[k * 68 + j0]);
        const float x0 = xr0[k], x1 = xr1[k], x2 = xr2[k], x3 = xr3[k];
        acc[0][0] = fmaf(x0, w.x, acc[0][0]); acc[0][1] = fmaf(x0, w.y, acc[0][1]);
        acc[0][2] = fmaf(x0, w.z, acc[0][2]); acc[0][3] = fmaf(x0, w.w, acc[0][3]);
        acc[1][0] = fmaf(x1, w.x, acc[1][0]); acc[1][1] = fmaf(x1, w.y, acc[1][1]);
        acc[1][2] = fmaf(x1, w.z, acc[1][2]); acc[1][3] = fmaf(x1, w.w, acc[1][3]);
        acc[2][0] = fmaf(x2, w.x, acc[2][0]); acc[2][1] = fmaf(x2, w.y, acc[2][1]);
        acc[2][2] = fmaf(x2, w.z, acc[2][2]); acc[2][3] = fmaf(x2, w.w, acc[2][3]);
        acc[3][0] = fmaf(x3, w.x, acc[3][0]); acc[3][1] = fmaf(x3, w.y, acc[3][1]);
        acc[3][2] = fmaf(x3, w.z, acc[3][2]); acc[3][3] = fmaf(x3, w.w, acc[3][3]);
    }

    __syncthreads();
    #pragma unroll
    for (int a = 0; a < 4; ++a)
        #pragma unroll
        for (int b = 0; b < 4; ++b)
            xs[(n0 + a) * 65 + j0 + b] = fmaxf(acc[a][b], 0.0f);
    __syncthreads();

    float acc2[4][4];
    #pragma unroll
    for (int a = 0; a < 4; ++a)
        #pragma unroll
        for (int b = 0; b < 4; ++b)
            acc2[a][b] = b2s[j0 + b];

    #pragma unroll 8
    for (int k = 0; k < 64; ++k) {
        const float4 w = *(const float4*)(&W2s[k * 68 + j0]);
        const float x0 = xr0[k], x1 = xr1[k], x2 = xr2[k], x3 = xr3[k];
        acc2[0][0] = fmaf(x0, w.x, acc2[0][0]); acc2[0][1] = fmaf(x0, w.y, acc2[0][1]);
        acc2[0][2] = fmaf(x0, w.z, acc2[0][2]); acc2[0][3] = fmaf(x0, w.w, acc2[0][3]);
        acc2[1][0] = fmaf(x1, w.x, acc2[1][0]); acc2[1][1] = fmaf(x1, w.y, acc2[1][1]);
        acc2[1][2] = fmaf(x1, w.z, acc2[1][2]); acc2[1][3] = fmaf(x1, w.w, acc2[1][3]);
        acc2[2][0] = fmaf(x2, w.x, acc2[2][0]); acc2[2][1] = fmaf(x2, w.y, acc2[2][1]);
        acc2[2][2] = fmaf(x2, w.z, acc2[2][2]); acc2[2][3] = fmaf(x2, w.w, acc2[2][3]);
        acc2[3][0] = fmaf(x3, w.x, acc2[3][0]); acc2[3][1] = fmaf(x3, w.y, acc2[3][1]);
        acc2[3][2] = fmaf(x3, w.z, acc2[3][2]); acc2[3][3] = fmaf(x3, w.w, acc2[3][3]);
    }

    float psum[4] = {0.f, 0.f, 0.f, 0.f};
    float psq[4]  = {0.f, 0.f, 0.f, 0.f};
    #pragma unroll
    for (int a = 0; a < 4; ++a) {
        int gn = nb + n0 + a;
        if (gn < N_NODES) {
            float4 hh;
            hh.x = acc2[a][0]; hh.y = acc2[a][1]; hh.z = acc2[a][2]; hh.w = acc2[a][3];
            *(float4*)(h2out + (size_t)gn * 64 + j0) = hh;
            psum[0] += hh.x; psq[0] += hh.x * hh.x;
            psum[1] += hh.y; psq[1] += hh.y * hh.y;
            psum[2] += hh.z; psq[2] += hh.z * hh.z;
            psum[3] += hh.w; psq[3] += hh.w * hh.w;
        }
    }
    #pragma unroll
    for (int off = 8; off >= 1; off >>= 1)
        #pragma unroll
        for (int b = 0; b < 4; ++b) {
            psum[b] += __shfl_down(psum[b], off, 16);
            psq[b]  += __shfl_down(psq[b],  off, 16);
        }
    if ((t & 15) == 0) {
        float* sp = stats8 + (size_t)(blockIdx.x & 7) * 128;
        #pragma unroll
        for (int b = 0; b < 4; ++b) {
            unsafeAtomicAdd(sp + j0 + b,      psum[b]);
            unsafeAtomicAdd(sp + 64 + j0 + b, psq[b]);
        }
    }
}

// ---------------------------------------------------------------------------
// bnstats_k: fold 8 stat shards -> scale/shift.
// ---------------------------------------------------------------------------
__global__ void bnstats_k(const float* __restrict__ stats8,
                          const float* __restrict__ gamma,
                          const float* __restrict__ beta,
                          float* __restrict__ sf)
{
    int j = threadIdx.x;
    float s = 0.f, q = 0.f;
    #pragma unroll
    for (int c = 0; c < 8; ++c) {
        s += stats8[c * 128 + j];
        q += stats8[c * 128 + 64 + j];
    }
    const float invN = 1.0f / (float)N_NODES;
    float mean  = s * invN;
    float var   = q * invN - mean * mean;
    float scale = gamma[j] * rsqrtf(var + BN_EPS);
    sf[j]      = scale;
    sf[64 + j] = beta[j] - mean * scale;
}

// ---------------------------------------------------------------------------
// finish16_k: out = relu(h2*scale + shift) + feat, h2 fp16.
// ---------------------------------------------------------------------------
__global__ __launch_bounds__(256) void finish16_k(
    const float* __restrict__ feat, const __half* __restrict__ h216,
    const float* __restrict__ sf, float* __restrict__ out)
{
    __shared__ float scs[64], shs[64];
    if (threadIdx.x < 64) {
        scs[threadIdx.x] = sf[threadIdx.x];
        shs[threadIdx.x] = sf[64 + threadIdx.x];
    }
    __syncthreads();
    size_t i = (size_t)blockIdx.x * 256 + threadIdx.x;
    if (i < (size_t)N_NODES * D / 4) {
        int j = (int)((i * 4) & 63);
        const __half2* hp = (const __half2*)(h216 + i * 4);
        float2 h0 = __half22float2(hp[0]);
        float2 h1 = __half22float2(hp[1]);
        float4 f = *(const float4*)(feat + i * 4);
        float4 o;
        o.x = fmaxf(fmaf(h0.x, scs[j + 0], shs[j + 0]), 0.f) + f.x;
        o.y = fmaxf(fmaf(h0.y, scs[j + 1], shs[j + 1]), 0.f) + f.y;
        o.z = fmaxf(fmaf(h1.x, scs[j + 2], shs[j + 2]), 0.f) + f.z;
        o.w = fmaxf(fmaf(h1.y, scs[j + 3], shs[j + 3]), 0.f) + f.w;
        *(float4*)(out + i * 4) = o;
    }
}

// ---------------------------------------------------------------------------
// finish_k (fp32 fallback, in-place on d_out).
// ---------------------------------------------------------------------------
__global__ __launch_bounds__(256) void finish_k(
    const float* __restrict__ feat, const float* __restrict__ sf,
    float* __restrict__ out)
{
    __shared__ float scs[64], shs[64];
    if (threadIdx.x < 64) {
        scs[threadIdx.x] = sf[threadIdx.x];
        shs[threadIdx.x] = sf[64 + threadIdx.x];
    }
    __syncthreads();
    size_t i = (size_t)blockIdx.x * 256 + threadIdx.x;
    if (i < (size_t)N_NODES * D / 4) {
        int j = (int)((i * 4) & 63);
        float4 h = *(float4*)(out + i * 4);
        float4 f = *(const float4*)(feat + i * 4);
        h.x = fmaxf(fmaf(h.x, scs[j + 0], shs[j + 0]), 0.f) + f.x;
        h.y = fmaxf(fmaf(h.y, scs[j + 1], shs[j + 1]), 0.f) + f.y;
        h.z = fmaxf(fmaf(h.z, scs[j + 2], shs[j + 2]), 0.f) + f.z;
        h.w = fmaxf(fmaf(h.w, scs[j + 3], shs[j + 3]), 0.f) + f.w;
        *(float4*)(out + i * 4) = h;
    }
}

extern "C" void kernel_launch(void* const* d_in, const int* in_sizes, int n_in,
                              void* d_out, int out_size, void* d_ws, size_t ws_size,
                              hipStream_t stream)
{
    const float* feat  = (const float*)d_in[0];
    const int*   src   = (const int*)d_in[1];
    const int*   dst   = (const int*)d_in[2];
    const float* eps   = (const float*)d_in[3];
    const float* W1    = (const float*)d_in[4];
    const float* b1    = (const float*)d_in[5];
    const float* W2    = (const float*)d_in[6];
    const float* b2    = (const float*)d_in[7];
    const float* gamma = (const float*)d_in[8];
    const float* beta  = (const float*)d_in[9];
    float* out = (float*)d_out;

    const size_t BKTSZ = (size_t)NBKT * BKT_CAP * sizeof(int2);   // 16.78 MB
    const size_t F16SZ = (size_t)N_NODES * D * sizeof(__half);    // 12.8 MB
    const size_t X32SZ = (size_t)N_NODES * D * sizeof(float);     // 25.6 MB
    const size_t COLSZ = (size_t)N_EDGES * sizeof(int);
    const size_t RPSZ  = (size_t)(N_NODES + 1) * sizeof(int);
    const size_t TAIL  = 1024 * 4 + NBKT * 4 + 128 * 4;
    const size_t need16 = BKTSZ + F16SZ + COLSZ + RPSZ + TAIL;    // ~36.4 MB

    if (ws_size >= need16) {
        // fp16 path. Aliases: x16 over bktbuf (dead after sort_k),
        // h216 over feat16 (dead after gather16_k).
        char* p = (char*)d_ws;
        __half* x16    = (__half*)p;
        int2*   bktbuf = (int2*)p;
        __half* feat16 = (__half*)(p + BKTSZ);
        __half* h216   = (__half*)(p + BKTSZ);                // == feat16
        int*    col    = (int*)(p + BKTSZ + F16SZ);
        int*    rowptr = col + N_EDGES;
        float*  stats8 = (float*)(rowptr + N_NODES + 1);
        int*    bkt_cnt = (int*)(stats8 + 1024);
        float*  sf     = (float*)(bkt_cnt + NBKT);

        hipMemsetAsync(stats8, 0, 1024 * 4 + NBKT * 4, stream);
        conv_k<<<3125, 256, 0, stream>>>(feat, feat16);
        bucket_k<<<(N_EDGES + 4095) / 4096, 256, 0, stream>>>(src, dst, bkt_cnt, bktbuf);
        sort_k<<<NBKT, SORT_T, 0, stream>>>(bktbuf, bkt_cnt, rowptr, col);
        gather16_k<<<(N_NODES + 3) / 4, 256, 0, stream>>>(feat16, rowptr, col, eps, x16);
        mfma_mlp_k<<<(N_NODES + 63) / 64, 256, 0, stream>>>(x16, W1, b1, W2, b2, h216, stats8);
        bnstats_k<<<1, 64, 0, stream>>>(stats8, gamma, beta, sf);
        finish16_k<<<(N_NODES * D / 4 + 255) / 256, 256, 0, stream>>>(feat, h216, sf, out);
    } else {
        // fp32 fallback (proven layout). x32 aliases bktbuf.
        char* p = (char*)d_ws;
        float* x32    = (float*)p;
        int2*  bktbuf = (int2*)p;
        int*   col    = (int*)(p + X32SZ);
        int*   rowptr = col + N_EDGES;
        float* stats8 = (float*)(rowptr + N_NODES + 1);
        int*   bkt_cnt = (int*)(stats8 + 1024);
        float* sf     = (float*)(bkt_cnt + NBKT);

        hipMemsetAsync(stats8, 0, 1024 * 4 + NBKT * 4, stream);
        bucket_k<<<(N_EDGES + 4095) / 4096, 256, 0, stream>>>(src, dst, bkt_cnt, bktbuf);
        sort_k<<<NBKT, SORT_T, 0, stream>>>(bktbuf, bkt_cnt, rowptr, col);
        gather32_k<<<(N_NODES + 3) / 4, 256, 0, stream>>>(feat, rowptr, col, eps, x32);
        mlp32_k<<<(N_NODES + 63) / 64, 256, 0, stream>>>(x32, W1, b1, W2, b2, out, stats8);
        bnstats_k<<<1, 64, 0, stream>>>(stats8, gamma, beta, sf);
        finish_k<<<(N_NODES * D / 4 + 255) / 256, 256, 0, stream>>>(feat, sf, out);
    }
}

// Round 9
// 220.690 us; speedup vs baseline: 1.1050x; 1.1050x over previous
//
#include <hip/hip_runtime.h>
#include <hip/hip_fp16.h>

#define N_NODES 100000
#define N_EDGES 1600000
#define D 64
#define BN_EPS 1e-5f
#define NBKT 256
#define NPB 391                  // nodes per bucket: 256*391 = 100096 >= 100000
#define BKT_CAP 7680             // expected ~6250/bucket, sigma ~79 (+18 sigma)
#define SORT_T 1024
#define NSHARD 64                // BN stat shards

typedef _Float16 half8 __attribute__((ext_vector_type(8)));
typedef float f32x4 __attribute__((ext_vector_type(4)));

// ---------------------------------------------------------------------------
// Bucket pass: split edges into 256 dst-range buckets ((src,dst) int2).
// ---------------------------------------------------------------------------
__global__ __launch_bounds__(256) void bucket_k(
    const int* __restrict__ src, const int* __restrict__ dst,
    int* __restrict__ bkt_cnt, int2* __restrict__ bktbuf)
{
    __shared__ int h[NBKT], base[NBKT], cur[NBKT];
    const int t = threadIdx.x;
    if (t < NBKT) { h[t] = 0; cur[t] = 0; }
    __syncthreads();
    const int e0 = blockIdx.x * 4096;
    int s[16], d[16], b[16];
    #pragma unroll
    for (int i = 0; i < 16; ++i) {
        int e = e0 + i * 256 + t;
        if (e < N_EDGES) {
            s[i] = src[e];
            d[i] = dst[e];
            b[i] = d[i] / NPB;
            atomicAdd(&h[b[i]], 1);
        } else {
            b[i] = -1;
        }
    }
    __syncthreads();
    if (t < NBKT) base[t] = atomicAdd(&bkt_cnt[t], h[t]);
    __syncthreads();
    #pragma unroll
    for (int i = 0; i < 16; ++i) {
        if (b[i] >= 0) {
            int p = atomicAdd(&cur[b[i]], 1);
            bktbuf[(size_t)b[i] * BKT_CAP + base[b[i]] + p] = make_int2(s[i], d[i]);
        }
    }
}

// ---------------------------------------------------------------------------
// sort_k: one block per bucket. LDS counting sort -> rowptr segment + col.
// ---------------------------------------------------------------------------
__global__ __launch_bounds__(SORT_T) void sort_k(
    const int2* __restrict__ bktbuf, const int* __restrict__ bkt_cnt,
    int* __restrict__ rowptr, int* __restrict__ col)
{
    __shared__ int h[NPB];
    __shared__ int cur[NPB];
    __shared__ int part[SORT_T];
    __shared__ int bsc[NBKT];

    const int b = blockIdx.x;
    const int t = threadIdx.x;
    const int nb0 = b * NPB;
    const int nodes_in = min(NPB, N_NODES - nb0);
    const int cnt = bkt_cnt[b];
    const int2* buf = bktbuf + (size_t)b * BKT_CAP;

    if (t < NBKT) bsc[t] = bkt_cnt[t];
    __syncthreads();
    for (int off = 1; off < NBKT; off <<= 1) {
        int x = 0;
        if (t < NBKT) {
            x = bsc[t];
            if (t >= off) x += bsc[t - off];
        }
        __syncthreads();
        if (t < NBKT) bsc[t] = x;
        __syncthreads();
    }
    const int gbase = bsc[b] - cnt;

    if (t < NPB) h[t] = 0;
    __syncthreads();

    for (int i = t; i < cnt; i += SORT_T)
        atomicAdd(&h[buf[i].y - nb0], 1);
    __syncthreads();

    int a = (t < NPB) ? h[t] : 0;
    part[t] = a;
    __syncthreads();
    for (int off = 1; off < SORT_T; off <<= 1) {
        int x = part[t];
        int u = (t >= off) ? part[t - off] : 0;
        __syncthreads();
        part[t] = x + u;
        __syncthreads();
    }
    int excl = part[t] - a;
    if (t < NPB) {
        cur[t] = excl;
        if (t < nodes_in) rowptr[nb0 + t] = gbase + excl;
    }
    if (b == NBKT - 1 && t == 0) rowptr[N_NODES] = N_EDGES;
    __syncthreads();

    for (int i = t; i < cnt; i += SORT_T) {
        int2 r = buf[i];
        int slot = atomicAdd(&cur[r.y - nb0], 1);
        col[gbase + slot] = r.x;
    }
}

// ---------------------------------------------------------------------------
// conv_k: feat fp32 -> fp16 table.
// ---------------------------------------------------------------------------
__global__ __launch_bounds__(256) void conv_k(
    const float* __restrict__ feat, __half* __restrict__ feat16)
{
    size_t i = ((size_t)blockIdx.x * 256 + threadIdx.x) * 8;
    if (i < (size_t)N_NODES * D) {
        float4 v0 = *(const float4*)(feat + i);
        float4 v1 = *(const float4*)(feat + i + 4);
        __half2 o[4];
        o[0] = __floats2half2_rn(v0.x, v0.y);
        o[1] = __floats2half2_rn(v0.z, v0.w);
        o[2] = __floats2half2_rn(v1.x, v1.y);
        o[3] = __floats2half2_rn(v1.z, v1.w);
        *(float4*)(feat16 + i) = *(float4*)o;
    }
}

// ---------------------------------------------------------------------------
// wprep_k: one block; W1,W2 (fp32 row-major [k][n]) -> global fp16 transposed
// tables w1t/w2t [n][k]. Runs once; mlp blocks then just vector-load frags.
// ---------------------------------------------------------------------------
__global__ __launch_bounds__(256) void wprep_k(
    const float* __restrict__ W1, const float* __restrict__ W2,
    _Float16* __restrict__ w1t, _Float16* __restrict__ w2t)
{
    const int t = threadIdx.x;
    const int n = t >> 2;
    const int k0 = (t & 3) * 16;
    _Float16 o1[16], o2[16];
    #pragma unroll
    for (int j = 0; j < 16; ++j) {
        o1[j] = (_Float16)W1[(k0 + j) * 64 + n];
        o2[j] = (_Float16)W2[(k0 + j) * 64 + n];
    }
    #pragma unroll
    for (int j = 0; j < 16; j += 8) {
        *(half8*)(w1t + n * 64 + k0 + j) = *(half8*)&o1[j];
        *(half8*)(w2t + n * 64 + k0 + j) = *(half8*)&o2[j];
    }
}

// ---------------------------------------------------------------------------
// gather16_k: one wave per node, fp16 rows (128B/edge), fp32 accumulate.
// Writes x = (1+eps)*feat + neigh in fp16.
// ---------------------------------------------------------------------------
__global__ __launch_bounds__(256) void gather16_k(
    const __half* __restrict__ feat16, const int* __restrict__ rowptr,
    const int* __restrict__ col, const float* __restrict__ epsp,
    __half* __restrict__ x16)
{
    int node = blockIdx.x * 4 + (threadIdx.x >> 6);
    int lane = threadIdx.x & 63;
    if (node >= N_NODES) return;
    int g = lane >> 3;
    int c = (lane & 7) << 3;
    int lo = rowptr[node];
    int hi = rowptr[node + 1];
    float a[8] = {0.f, 0.f, 0.f, 0.f, 0.f, 0.f, 0.f, 0.f};
    int e = lo + g;
    for (; e + 8 < hi; e += 16) {
        int s0 = col[e];
        int s1 = col[e + 8];
        float4 r0 = *(const float4*)(feat16 + (size_t)s0 * D + c);
        float4 r1 = *(const float4*)(feat16 + (size_t)s1 * D + c);
        const __half2* h0 = (const __half2*)&r0;
        const __half2* h1 = (const __half2*)&r1;
        #pragma unroll
        for (int i = 0; i < 4; ++i) {
            float2 f0 = __half22float2(h0[i]);
            float2 f1 = __half22float2(h1[i]);
            a[2 * i]     += f0.x + f1.x;
            a[2 * i + 1] += f0.y + f1.y;
        }
    }
    if (e < hi) {
        float4 r0 = *(const float4*)(feat16 + (size_t)col[e] * D + c);
        const __half2* h0 = (const __half2*)&r0;
        #pragma unroll
        for (int i = 0; i < 4; ++i) {
            float2 f0 = __half22float2(h0[i]);
            a[2 * i]     += f0.x;
            a[2 * i + 1] += f0.y;
        }
    }
    #pragma unroll
    for (int off = 8; off <= 32; off <<= 1)
        #pragma unroll
        for (int i = 0; i < 8; ++i)
            a[i] += __shfl_xor(a[i], off, 64);
    if (g == 0) {
        float4 rs = *(const float4*)(feat16 + (size_t)node * D + c);
        const __half2* hs = (const __half2*)&rs;
        const float epsv = 1.0f + epsp[0];
        __half2 o[4];
        #pragma unroll
        for (int i = 0; i < 4; ++i) {
            float2 fs = __half22float2(hs[i]);
            o[i] = __floats2half2_rn(fmaf(epsv, fs.x, a[2 * i]),
                                     fmaf(epsv, fs.y, a[2 * i + 1]));
        }
        *(float4*)(x16 + (size_t)node * D + c) = *(float4*)o;
    }
}

// ---------------------------------------------------------------------------
// gather32_k (fp32 fallback).
// ---------------------------------------------------------------------------
__global__ __launch_bounds__(256) void gather32_k(
    const float* __restrict__ feat, const int* __restrict__ rowptr,
    const int* __restrict__ col, const float* __restrict__ epsp,
    float* __restrict__ x)
{
    int node = blockIdx.x * 4 + (threadIdx.x >> 6);
    int lane = threadIdx.x & 63;
    if (node >= N_NODES) return;
    int g = lane >> 4;
    int c = (lane & 15) << 2;
    int lo = rowptr[node];
    int hi = rowptr[node + 1];
    float ax = 0.f, ay = 0.f, az = 0.f, aw = 0.f;
    int e = lo + g;
    for (; e + 4 < hi; e += 8) {
        int s0 = col[e];
        int s1 = col[e + 4];
        float4 v0 = *(const float4*)(feat + (size_t)s0 * D + c);
        float4 v1 = *(const float4*)(feat + (size_t)s1 * D + c);
        ax += v0.x; ay += v0.y; az += v0.z; aw += v0.w;
        ax += v1.x; ay += v1.y; az += v1.z; aw += v1.w;
    }
    if (e < hi) {
        float4 v = *(const float4*)(feat + (size_t)col[e] * D + c);
        ax += v.x; ay += v.y; az += v.z; aw += v.w;
    }
    #pragma unroll
    for (int off = 16; off <= 32; off <<= 1) {
        ax += __shfl_xor(ax, off, 64);
        ay += __shfl_xor(ay, off, 64);
        az += __shfl_xor(az, off, 64);
        aw += __shfl_xor(aw, off, 64);
    }
    if (g == 0) {
        float4 f = *(const float4*)(feat + (size_t)node * D + c);
        const float epsv = 1.0f + epsp[0];
        float4 r;
        r.x = fmaf(epsv, f.x, ax);
        r.y = fmaf(epsv, f.y, ay);
        r.z = fmaf(epsv, f.z, az);
        r.w = fmaf(epsv, f.w, aw);
        *(float4*)(x + (size_t)node * D + c) = r;
    }
}

// ---------------------------------------------------------------------------
// mfma_mlp2_k: barrier-free MFMA MLP. One block = 64 nodes = 4 waves;
// wave w privately owns nodes/LDS-rows 16w..16w+15. A-frags straight from
// global x16 (L2-warm), B-frags straight from global w1t/w2t (L2-broadcast).
// Only LDS use: wave-private relu-transpose / h2-staging slab (9.2 KB).
// Intra-wave LDS ordering via s_waitcnt lgkmcnt(0) — NO __syncthreads.
// BN partials -> 64-shard global atomics (blockIdx & 63).
// ---------------------------------------------------------------------------
__global__ __launch_bounds__(256) void mfma_mlp2_k(
    const __half* __restrict__ x16,
    const _Float16* __restrict__ w1t, const _Float16* __restrict__ w2t,
    const float* __restrict__ b1, const float* __restrict__ b2,
    __half* __restrict__ h216, float* __restrict__ stats)
{
    __shared__ __align__(16) _Float16 xts[64 * 72];

    const int t    = threadIdx.x;
    const int w    = t >> 6;
    const int lane = t & 63;
    const int m    = lane & 15;   // A row / C col (within 16-tile)
    const int q    = lane >> 4;   // k-subchunk / C row-quad
    const int rbase = w * 16;
    const int nb   = blockIdx.x * 64;

    // A-frags direct from global (row nb+rbase+m, k q*8.. and +32)
    const _Float16* xg = (const _Float16*)x16 + (size_t)(nb + rbase + m) * 64 + q * 8;
    half8 a0 = *(const half8*)(xg);
    half8 a1 = *(const half8*)(xg + 32);

    // GEMM1: h1 = x @ W1 + b1
    f32x4 acc[4];
    #pragma unroll
    for (int jt = 0; jt < 4; ++jt) {
        const float bias = b1[jt * 16 + m];
        acc[jt] = (f32x4){bias, bias, bias, bias};
        const _Float16* bw = w1t + (jt * 16 + m) * 64 + q * 8;
        half8 bf0 = *(const half8*)(bw);
        half8 bf1 = *(const half8*)(bw + 32);
        acc[jt] = __builtin_amdgcn_mfma_f32_16x16x32_f16(a0, bf0, acc[jt], 0, 0, 0);
        acc[jt] = __builtin_amdgcn_mfma_f32_16x16x32_f16(a1, bf1, acc[jt], 0, 0, 0);
    }

    // relu -> wave-private LDS transpose (C-layout -> A-layout)
    #pragma unroll
    for (int jt = 0; jt < 4; ++jt)
        #pragma unroll
        for (int r = 0; r < 4; ++r)
            xts[(rbase + q * 4 + r) * 72 + jt * 16 + m] =
                (_Float16)fmaxf(acc[jt][r], 0.0f);
    asm volatile("s_waitcnt lgkmcnt(0)" ::: "memory");

    const _Float16* xw = &xts[(rbase + m) * 72 + q * 8];
    half8 c0 = *(const half8*)(xw);
    half8 c1 = *(const half8*)(xw + 32);

    // GEMM2: h2 = t @ W2 + b2
    f32x4 acc2[4];
    #pragma unroll
    for (int jt = 0; jt < 4; ++jt) {
        const float bias = b2[jt * 16 + m];
        acc2[jt] = (f32x4){bias, bias, bias, bias};
        const _Float16* bw = w2t + (jt * 16 + m) * 64 + q * 8;
        half8 bf0 = *(const half8*)(bw);
        half8 bf1 = *(const half8*)(bw + 32);
        acc2[jt] = __builtin_amdgcn_mfma_f32_16x16x32_f16(c0, bf0, acc2[jt], 0, 0, 0);
        acc2[jt] = __builtin_amdgcn_mfma_f32_16x16x32_f16(c1, bf1, acc2[jt], 0, 0, 0);
    }
    asm volatile("s_waitcnt lgkmcnt(0)" ::: "memory");  // c0/c1 reads done before overwrite

    // BN partials + stage h2 into the (reused) wave-private slab
    float psums[4], psqs[4];
    #pragma unroll
    for (int jt = 0; jt < 4; ++jt) {
        float ps = 0.f, pq = 0.f;
        #pragma unroll
        for (int r = 0; r < 4; ++r) {
            const int row = rbase + q * 4 + r;
            const float v = acc2[jt][r];
            const float vv = (nb + row < N_NODES) ? v : 0.f;
            ps += vv;
            pq += vv * vv;
            xts[row * 72 + jt * 16 + m] = (_Float16)v;
        }
        ps += __shfl_xor(ps, 16, 64); ps += __shfl_xor(ps, 32, 64);
        pq += __shfl_xor(pq, 16, 64); pq += __shfl_xor(pq, 32, 64);
        psums[jt] = ps; psqs[jt] = pq;
    }
    if (lane < 16) {
        float* sp = stats + (size_t)(blockIdx.x & (NSHARD - 1)) * 128;
        #pragma unroll
        for (int jt = 0; jt < 4; ++jt) {
            unsafeAtomicAdd(sp + jt * 16 + lane,      psums[jt]);
            unsafeAtomicAdd(sp + 64 + jt * 16 + lane, psqs[jt]);
        }
    }
    asm volatile("s_waitcnt lgkmcnt(0)" ::: "memory");

    // coalesced fp16 h2 store (wave reads back only its own 16 rows)
    {
        const int rr = lane >> 2;
        const int cc = (lane & 3) * 16;
        const int gn = nb + rbase + rr;
        if (gn < N_NODES) {
            float4 r0 = *(const float4*)&xts[(rbase + rr) * 72 + cc];
            float4 r1 = *(const float4*)&xts[(rbase + rr) * 72 + cc + 8];
            *(float4*)(h216 + (size_t)gn * 64 + cc)     = r0;
            *(float4*)(h216 + (size_t)gn * 64 + cc + 8) = r1;
        }
    }
}

// ---------------------------------------------------------------------------
// mlp32_k (fp32 fallback): scalar-FMA MLP, h2 fp32 into h2out.
// ---------------------------------------------------------------------------
__global__ __launch_bounds__(256) void mlp32_k(
    const float* __restrict__ x,
    const float* __restrict__ W1, const float* __restrict__ b1,
    const float* __restrict__ W2, const float* __restrict__ b2,
    float* __restrict__ h2out, float* __restrict__ stats)
{
    __shared__ float W1s[64 * 68];
    __shared__ float W2s[64 * 68];
    __shared__ float xs[64 * 65];
    __shared__ float b1s[64], b2s[64];

    const int t  = threadIdx.x;
    const int nb = blockIdx.x * 64;

    #pragma unroll
    for (int i = 0; i < 4; ++i) {
        int l  = t + i * 256;
        int k  = l >> 4;
        int j4 = (l & 15) << 2;
        *(float4*)(&W1s[k * 68 + j4]) = *(const float4*)(W1 + k * 64 + j4);
        *(float4*)(&W2s[k * 68 + j4]) = *(const float4*)(W2 + k * 64 + j4);
    }
    if (t < 64)       b1s[t]      = b1[t];
    else if (t < 128) b2s[t - 64] = b2[t - 64];

    #pragma unroll
    for (int i = 0; i < 2; ++i) {
        int n  = (t >> 3) + i * 32;
        int k8 = (t & 7) << 3;
        int gn = nb + n;
        float4 a = make_float4(0.f, 0.f, 0.f, 0.f), b = a;
        if (gn < N_NODES) {
            a = *(const float4*)(x + (size_t)gn * D + k8);
            b = *(const float4*)(x + (size_t)gn * D + k8 + 4);
        }
        *(float4*)&xs[n * 65 + k8]     = a;
        *(float4*)&xs[n * 65 + k8 + 4] = b;
    }
    __syncthreads();

    const int n0 = (t & 15) << 2;
    const int j0 = (t >> 4) << 2;
    const float* xr0 = &xs[(n0 + 0) * 65];
    const float* xr1 = &xs[(n0 + 1) * 65];
    const float* xr2 = &xs[(n0 + 2) * 65];
    const float* xr3 = &xs[(n0 + 3) * 65];

    float acc[4][4];
    #pragma unroll
    for (int a = 0; a < 4; ++a)
        #pragma unroll
        for (int b = 0; b < 4; ++b)
            acc[a][b] = b1s[j0 + b];

    #pragma unroll 8
    for (int k = 0; k < 64; ++k) {
        const float4 w = *(const float4*)(&W1s[k * 68 + j0]);
        const float x0 = xr0[k], x1 = xr1[k], x2 = xr2[k], x3 = xr3[k];
        acc[0][0] = fmaf(x0, w.x, acc[0][0]); acc[0][1] = fmaf(x0, w.y, acc[0][1]);
        acc[0][2] = fmaf(x0, w.z, acc[0][2]); acc[0][3] = fmaf(x0, w.w, acc[0][3]);
        acc[1][0] = fmaf(x1, w.x, acc[1][0]); acc[1][1] = fmaf(x1, w.y, acc[1][1]);
        acc[1][2] = fmaf(x1, w.z, acc[1][2]); acc[1][3] = fmaf(x1, w.w, acc[1][3]);
        acc[2][0] = fmaf(x2, w.x, acc[2][0]); acc[2][1] = fmaf(x2, w.y, acc[2][1]);
        acc[2][2] = fmaf(x2, w.z, acc[2][2]); acc[2][3] = fmaf(x2, w.w, acc[2][3]);
        acc[3][0] = fmaf(x3, w.x, acc[3][0]); acc[3][1] = fmaf(x3, w.y, acc[3][1]);
        acc[3][2] = fmaf(x3, w.z, acc[3][2]); acc[3][3] = fmaf(x3, w.w, acc[3][3]);
    }

    __syncthreads();
    #pragma unroll
    for (int a = 0; a < 4; ++a)
        #pragma unroll
        for (int b = 0; b < 4; ++b)
            xs[(n0 + a) * 65 + j0 + b] = fmaxf(acc[a][b], 0.0f);
    __syncthreads();

    float acc2[4][4];
    #pragma unroll
    for (int a = 0; a < 4; ++a)
        #pragma unroll
        for (int b = 0; b < 4; ++b)
            acc2[a][b] = b2s[j0 + b];

    #pragma unroll 8
    for (int k = 0; k < 64; ++k) {
        const float4 w = *(const float4*)(&W2s[k * 68 + j0]);
        const float x0 = xr0[k], x1 = xr1[k], x2 = xr2[k], x3 = xr3[k];
        acc2[0][0] = fmaf(x0, w.x, acc2[0][0]); acc2[0][1] = fmaf(x0, w.y, acc2[0][1]);
        acc2[0][2] = fmaf(x0, w.z, acc2[0][2]); acc2[0][3] = fmaf(x0, w.w, acc2[0][3]);
        acc2[1][0] = fmaf(x1, w.x, acc2[1][0]); acc2[1][1] = fmaf(x1, w.y, acc2[1][1]);
        acc2[1][2] = fmaf(x1, w.z, acc2[1][2]); acc2[1][3] = fmaf(x1, w.w, acc2[1][3]);
        acc2[2][0] = fmaf(x2, w.x, acc2[2][0]); acc2[2][1] = fmaf(x2, w.y, acc2[2][1]);
        acc2[2][2] = fmaf(x2, w.z, acc2[2][2]); acc2[2][3] = fmaf(x2, w.w, acc2[2][3]);
        acc2[3][0] = fmaf(x3, w.x, acc2[3][0]); acc2[3][1] = fmaf(x3, w.y, acc2[3][1]);
        acc2[3][2] = fmaf(x3, w.z, acc2[3][2]); acc2[3][3] = fmaf(x3, w.w, acc2[3][3]);
    }

    float psum[4] = {0.f, 0.f, 0.f, 0.f};
    float psq[4]  = {0.f, 0.f, 0.f, 0.f};
    #pragma unroll
    for (int a = 0; a < 4; ++a) {
        int gn = nb + n0 + a;
        if (gn < N_NODES) {
            float4 hh;
            hh.x = acc2[a][0]; hh.y = acc2[a][1]; hh.z = acc2[a][2]; hh.w = acc2[a][3];
            *(float4*)(h2out + (size_t)gn * 64 + j0) = hh;
            psum[0] += hh.x; psq[0] += hh.x * hh.x;
            psum[1] += hh.y; psq[1] += hh.y * hh.y;
            psum[2] += hh.z; psq[2] += hh.z * hh.z;
            psum[3] += hh.w; psq[3] += hh.w * hh.w;
        }
    }
    #pragma unroll
    for (int off = 8; off >= 1; off >>= 1)
        #pragma unroll
        for (int b = 0; b < 4; ++b) {
            psum[b] += __shfl_down(psum[b], off, 16);
            psq[b]  += __shfl_down(psq[b],  off, 16);
        }
    if ((t & 15) == 0) {
        float* sp = stats + (size_t)(blockIdx.x & (NSHARD - 1)) * 128;
        #pragma unroll
        for (int b = 0; b < 4; ++b) {
            unsafeAtomicAdd(sp + j0 + b,      psum[b]);
            unsafeAtomicAdd(sp + 64 + j0 + b, psq[b]);
        }
    }
}

// ---------------------------------------------------------------------------
// bnstats_k: fold NSHARD stat shards -> scale/shift.
// ---------------------------------------------------------------------------
__global__ void bnstats_k(const float* __restrict__ stats,
                          const float* __restrict__ gamma,
                          const float* __restrict__ beta,
                          float* __restrict__ sf)
{
    int j = threadIdx.x;
    float s = 0.f, q = 0.f;
    for (int c = 0; c < NSHARD; ++c) {
        s += stats[c * 128 + j];
        q += stats[c * 128 + 64 + j];
    }
    const float invN = 1.0f / (float)N_NODES;
    float mean  = s * invN;
    float var   = q * invN - mean * mean;
    float scale = gamma[j] * rsqrtf(var + BN_EPS);
    sf[j]      = scale;
    sf[64 + j] = beta[j] - mean * scale;
}

// ---------------------------------------------------------------------------
// finish16_k: out = relu(h2*scale + shift) + feat, h2 fp16.
// ---------------------------------------------------------------------------
__global__ __launch_bounds__(256) void finish16_k(
    const float* __restrict__ feat, const __half* __restrict__ h216,
    const float* __restrict__ sf, float* __restrict__ out)
{
    __shared__ float scs[64], shs[64];
    if (threadIdx.x < 64) {
        scs[threadIdx.x] = sf[threadIdx.x];
        shs[threadIdx.x] = sf[64 + threadIdx.x];
    }
    __syncthreads();
    size_t i = (size_t)blockIdx.x * 256 + threadIdx.x;
    if (i < (size_t)N_NODES * D / 4) {
        int j = (int)((i * 4) & 63);
        const __half2* hp = (const __half2*)(h216 + i * 4);
        float2 h0 = __half22float2(hp[0]);
        float2 h1 = __half22float2(hp[1]);
        float4 f = *(const float4*)(feat + i * 4);
        float4 o;
        o.x = fmaxf(fmaf(h0.x, scs[j + 0], shs[j + 0]), 0.f) + f.x;
        o.y = fmaxf(fmaf(h0.y, scs[j + 1], shs[j + 1]), 0.f) + f.y;
        o.z = fmaxf(fmaf(h1.x, scs[j + 2], shs[j + 2]), 0.f) + f.z;
        o.w = fmaxf(fmaf(h1.y, scs[j + 3], shs[j + 3]), 0.f) + f.w;
        *(float4*)(out + i * 4) = o;
    }
}

// ---------------------------------------------------------------------------
// finish_k (fp32 fallback, in-place on d_out).
// ---------------------------------------------------------------------------
__global__ __launch_bounds__(256) void finish_k(
    const float* __restrict__ feat, const float* __restrict__ sf,
    float* __restrict__ out)
{
    __shared__ float scs[64], shs[64];
    if (threadIdx.x < 64) {
        scs[threadIdx.x] = sf[threadIdx.x];
        shs[threadIdx.x] = sf[64 + threadIdx.x];
    }
    __syncthreads();
    size_t i = (size_t)blockIdx.x * 256 + threadIdx.x;
    if (i < (size_t)N_NODES * D / 4) {
        int j = (int)((i * 4) & 63);
        float4 h = *(float4*)(out + i * 4);
        float4 f = *(const float4*)(feat + i * 4);
        h.x = fmaxf(fmaf(h.x, scs[j + 0], shs[j + 0]), 0.f) + f.x;
        h.y = fmaxf(fmaf(h.y, scs[j + 1], shs[j + 1]), 0.f) + f.y;
        h.z = fmaxf(fmaf(h.z, scs[j + 2], shs[j + 2]), 0.f) + f.z;
        h.w = fmaxf(fmaf(h.w, scs[j + 3], shs[j + 3]), 0.f) + f.w;
        *(float4*)(out + i * 4) = h;
    }
}

extern "C" void kernel_launch(void* const* d_in, const int* in_sizes, int n_in,
                              void* d_out, int out_size, void* d_ws, size_t ws_size,
                              hipStream_t stream)
{
    const float* feat  = (const float*)d_in[0];
    const int*   src   = (const int*)d_in[1];
    const int*   dst   = (const int*)d_in[2];
    const float* eps   = (const float*)d_in[3];
    const float* W1    = (const float*)d_in[4];
    const float* b1    = (const float*)d_in[5];
    const float* W2    = (const float*)d_in[6];
    const float* b2    = (const float*)d_in[7];
    const float* gamma = (const float*)d_in[8];
    const float* beta  = (const float*)d_in[9];
    float* out = (float*)d_out;

    const size_t BKTSZ = (size_t)NBKT * BKT_CAP * sizeof(int2);   // 15.7 MB
    const size_t F16SZ = (size_t)N_NODES * D * sizeof(__half);    // 12.8 MB
    const size_t X32SZ = (size_t)N_NODES * D * sizeof(float);     // 25.6 MB
    const size_t COLSZ = (size_t)N_EDGES * sizeof(int);
    const size_t RPSZ  = (size_t)(N_NODES + 1) * sizeof(int);
    const size_t STATSZ = (size_t)NSHARD * 128 * sizeof(float);   // 32 KB
    const size_t TAIL  = STATSZ + NBKT * 4 + 128 * 4 + 2 * 4096 * sizeof(_Float16) + 256;
    const size_t need16 = BKTSZ + F16SZ + COLSZ + RPSZ + TAIL;    // ~35.5 MB

    if (ws_size >= need16) {
        // fp16 path. Aliases: x16 over bktbuf (dead after sort_k),
        // h216 over feat16 (dead after gather16_k).
        char* p = (char*)d_ws;
        __half* x16    = (__half*)p;
        int2*   bktbuf = (int2*)p;
        __half* feat16 = (__half*)(p + BKTSZ);
        __half* h216   = (__half*)(p + BKTSZ);                // == feat16
        int*    col    = (int*)(p + BKTSZ + F16SZ);
        int*    rowptr = col + N_EDGES;
        float*  stats  = (float*)(rowptr + N_NODES + 1);
        int*    bkt_cnt = (int*)(stats + NSHARD * 128);
        float*  sf     = (float*)(bkt_cnt + NBKT);
        _Float16* w1t  = (_Float16*)(sf + 128);
        _Float16* w2t  = w1t + 4096;

        hipMemsetAsync(stats, 0, STATSZ + NBKT * 4, stream);
        conv_k<<<3125, 256, 0, stream>>>(feat, feat16);
        wprep_k<<<1, 256, 0, stream>>>(W1, W2, w1t, w2t);
        bucket_k<<<(N_EDGES + 4095) / 4096, 256, 0, stream>>>(src, dst, bkt_cnt, bktbuf);
        sort_k<<<NBKT, SORT_T, 0, stream>>>(bktbuf, bkt_cnt, rowptr, col);
        gather16_k<<<(N_NODES + 3) / 4, 256, 0, stream>>>(feat16, rowptr, col, eps, x16);
        mfma_mlp2_k<<<(N_NODES + 63) / 64, 256, 0, stream>>>(x16, w1t, w2t, b1, b2, h216, stats);
        bnstats_k<<<1, 64, 0, stream>>>(stats, gamma, beta, sf);
        finish16_k<<<(N_NODES * D / 4 + 255) / 256, 256, 0, stream>>>(feat, h216, sf, out);
    } else {
        // fp32 fallback. x32 aliases bktbuf.
        char* p = (char*)d_ws;
        float* x32    = (float*)p;
        int2*  bktbuf = (int2*)p;
        int*   col    = (int*)(p + X32SZ);
        int*   rowptr = col + N_EDGES;
        float* stats  = (float*)(rowptr + N_NODES + 1);
        int*   bkt_cnt = (int*)(stats + NSHARD * 128);
        float* sf     = (float*)(bkt_cnt + NBKT);

        hipMemsetAsync(stats, 0, STATSZ + NBKT * 4, stream);
        bucket_k<<<(N_EDGES + 4095) / 4096, 256, 0, stream>>>(src, dst, bkt_cnt, bktbuf);
        sort_k<<<NBKT, SORT_T, 0, stream>>>(bktbuf, bkt_cnt, rowptr, col);
        gather32_k<<<(N_NODES + 3) / 4, 256, 0, stream>>>(feat, rowptr, col, eps, x32);
        mlp32_k<<<(N_NODES + 63) / 64, 256, 0, stream>>>(x32, W1, b1, W2, b2, out, stats);
        bnstats_k<<<1, 64, 0, stream>>>(stats, gamma, beta, sf);
        finish_k<<<(N_NODES * D / 4 + 255) / 256, 256, 0, stream>>>(feat, sf, out);
    }
}